// Round 12
// baseline (260.017 us; speedup 1.0000x reference)
//
#include <hip/hip_runtime.h>
#include <hip/hip_bf16.h>
#include <cstdint>
#include <cstddef>

// Problem constants
#define SEQ    4096
#define NB     4
#define DIM    1024
#define NHEAD  16
#define HDIM   64
#define MROWS  (NB * SEQ)   // 16384
#define SCALEF 0.125f       // 64^-0.5
#define NT     16           // K tiles of 64

typedef short          s16x8 __attribute__((ext_vector_type(8)));
typedef unsigned short u16x8 __attribute__((ext_vector_type(8)));
typedef float          f32x4 __attribute__((ext_vector_type(4)));
typedef unsigned short u16;

__device__ __forceinline__ u16 f2bf(float f) {
  return __builtin_bit_cast(u16, __float2bfloat16(f));
}
__device__ __forceinline__ float bf2f(u16 u) {
  return __builtin_bit_cast(float, (uint32_t)u << 16);
}
__device__ __forceinline__ void gload_lds16(const void* g, void* l) {
  __builtin_amdgcn_global_load_lds(
      (const __attribute__((address_space(1))) void*)g,
      (__attribute__((address_space(3))) void*)l, 16, 0, 0);
}

// ---------------------------------------------------------------------------
// Convert the four [DIM,DIM] fp32 weight matrices to bf16.
// ---------------------------------------------------------------------------
__global__ __launch_bounds__(256) void cvt_weights(
    const float* __restrict__ w0, const float* __restrict__ w1,
    const float* __restrict__ w2, const float* __restrict__ w3,
    u16* __restrict__ o0, u16* __restrict__ o1,
    u16* __restrict__ o2, u16* __restrict__ o3)
{
  int t = blockIdx.x * 256 + threadIdx.x;
  int m = t >> 17;
  int off = (t & 131071) * 8;
  const float* s = (m == 0) ? w0 : (m == 1) ? w1 : (m == 2) ? w2 : w3;
  u16*         d = (m == 0) ? o0 : (m == 1) ? o1 : (m == 2) ? o2 : o3;
  float4 a = ((const float4*)(s + off))[0];
  float4 b = ((const float4*)(s + off))[1];
  u16x8 p;
  p[0] = f2bf(a.x); p[1] = f2bf(a.y); p[2] = f2bf(a.z); p[3] = f2bf(a.w);
  p[4] = f2bf(b.x); p[5] = f2bf(b.y); p[6] = f2bf(b.z); p[7] = f2bf(b.w);
  *(u16x8*)(d + off) = p;
}

// ---------------------------------------------------------------------------
// 256x256-tile phase-split GEMM (T2+T3+T4+T5), BK=64, 8 waves (2Mx4N), 512thr.
// LDS (dynamic 128KB): A[2][256][64] bf16 @0, B[2][256][64] bf16 @65536.
// T2 swizzle both-sides (verified r6: bank conflicts 1.26e7 -> 0).
// r11: B-fragments hoisted (breg_all loaded once per tile at p0).
// r12 CHANGE (AF32=1, MODE0): A is staged DIRECTLY FROM FP32 via registers
// (T14 issue-early/write-late), eliminating the 3 serial cvt_act passes
// (~47us at BW floor). Per half-tile: 4x dwordx4 -> v_cvt_pk -> 2x
// ds_write_b128 with the T2 swizzle applied on the WRITE address (read side
// unchanged; gload_lds no longer involved for A so rule #21 is satisfied).
// vmcnt ledger (per tile, wave issue order):
//   p0: A1ld(t+1) [4 ops]
//   p1: vmcnt(4)  [A0ld(t+1) done; newer = A1ld(4)]   wrA0(t+1); B0 gload(2)
//   p2: vmcnt(2)  [A1ld done; newer = B0(2)]          wrA1(t+1); B1 gload(2)
//   p3: A0ld(t+2) [4]; vmcnt(4) [B0,B1 landed; newer = A0ld(4)]; lgkmcnt(0)
// Tail: t+1>=NT skips stage+waits; t==NT-2 uses vmcnt(0) (A0ld skipped).
// NOTE (r7-r9): keep 512 threads; >512-thread variants spill acc to scratch.
// MODE 0 (AF32=1): C = f32A@W^T + bias -> bf16 (+optional alpha logits).
// MODE 1 (AF32=0): C = bf16A@W^T + c2[batch] -> fp32 (r11 path, verified).
// ---------------------------------------------------------------------------
template<int MODE, int AF32>
__global__ __launch_bounds__(512) void gemm256(
    const u16* __restrict__ A, const u16* __restrict__ W,
    const float* __restrict__ bias, u16* __restrict__ Cb, float* __restrict__ Cf,
    const float* __restrict__ c2, int do_alpha,
    const float* __restrict__ qalpha, float* __restrict__ la,
    const float* __restrict__ Af)
{
  extern __shared__ __align__(16) char smem[];
  const int tid = threadIdx.x;
  const int lane = tid & 63, wave = tid >> 6;
  const int wr = wave >> 2, wc = wave & 3;          // 2 (M) x 4 (N)
  const int fr = lane & 15, fq = lane >> 4;
  const int m0 = blockIdx.x * 256, n0 = blockIdx.y * 256;
  const int wrow = wr * 128, wcol = wc * 64;

  const int arow = tid >> 3;                         // staging row 0..63
  const int acnk = tid & 7;                          // staging chunk 0..7
  const int scol = ((acnk ^ (arow & 7)) * 8);        // pre-swizzled src col (B)

  f32x4 acc[8][4];
  #pragma unroll
  for (int i = 0; i < 8; ++i)
    #pragma unroll
    for (int j = 0; j < 4; ++j) acc[i][j] = (f32x4){0.f, 0.f, 0.f, 0.f};

  auto stA = [&](int kt, int h) {                    // bf16 A path (AF32=0)
    const u16* g = A + (size_t)(m0 + h * 128) * DIM + kt * 64;
    char* l = smem + (kt & 1) * 32768 + h * 16384;
    gload_lds16(g + (size_t)arow * DIM + scol,        l + tid * 16);
    gload_lds16(g + (size_t)(64 + arow) * DIM + scol, l + 8192 + tid * 16);
  };
  auto stB = [&](int kt, int h) {
    const u16* g = W + (size_t)(n0 + h * 128) * DIM + kt * 64;
    char* l = smem + 65536 + (kt & 1) * 32768 + h * 16384;
    gload_lds16(g + (size_t)arow * DIM + scol,        l + tid * 16);
    gload_lds16(g + (size_t)(64 + arow) * DIM + scol, l + 8192 + tid * 16);
  };
  // fp32 A: issue 4 dwordx4 loads (rows arow, 64+arow; linear source cols)
  auto ldA4 = [&](int kt, int h, f32x4* r) {
    const float* g = Af + (size_t)(m0 + h * 128 + arow) * DIM + kt * 64 + acnk * 8;
    r[0] = *(const f32x4*)g;
    r[1] = *(const f32x4*)(g + 4);
    const float* g2 = g + (size_t)64 * DIM;
    r[2] = *(const f32x4*)g2;
    r[3] = *(const f32x4*)(g2 + 4);
  };
  // fp32 A: cvt + swizzled ds_write (write addr carries the T2 involution)
  auto wrA = [&](int kt, int h, const f32x4* r) {
    char* l = smem + (kt & 1) * 32768 + h * 16384;
    const int wb = arow * 128 + ((acnk ^ (arow & 7)) << 4);
    u16x8 p0, p1;
    #pragma unroll
    for (int j = 0; j < 4; ++j) { p0[j] = f2bf(r[0][j]); p0[4 + j] = f2bf(r[1][j]); }
    #pragma unroll
    for (int j = 0; j < 4; ++j) { p1[j] = f2bf(r[2][j]); p1[4 + j] = f2bf(r[3][j]); }
    *(u16x8*)(l + wb) = p0;
    *(u16x8*)(l + 8192 + wb) = p1;                   // row 64+arow (same row&7)
  };
  auto ldsoff = [&](int R, int ks) -> size_t {
    return (size_t)R * 128 + (size_t)((ks * 64 + fq * 16) ^ ((R & 7) << 4));
  };

  f32x4 rA0[4], rA1[4], r00[4], r01[4];

  // ---- prologue ----
  if constexpr (AF32) {
    ldA4(0, 0, r00); ldA4(0, 1, r01);                // 8 ops
    stB(0, 0); stB(0, 1);                            // 4 ops
    ldA4(1, 0, rA0);                                 // 4 ops
    asm volatile("s_waitcnt vmcnt(8)" ::: "memory"); // r00,r01 done
    wrA(0, 0, r00); wrA(0, 1, r01);
    asm volatile("s_waitcnt vmcnt(4)" ::: "memory"); // B(0) landed
    asm volatile("s_waitcnt lgkmcnt(0)" ::: "memory");
  } else {
    stA(0, 0); stA(0, 1); stB(0, 0); stB(0, 1);
    stA(1, 0);
    asm volatile("s_waitcnt vmcnt(2)" ::: "memory");
  }
  asm volatile("s_barrier" ::: "memory");

  for (int t = 0; t < NT; ++t) {
    const char* Abase = smem + (t & 1) * 32768;
    const char* Bbase = smem + 65536 + (t & 1) * 32768;
    s16x8 areg[4][2];
    s16x8 breg_all[4][2];            // all 4 nj x 2 ks, loaded once at p==0
    #pragma unroll
    for (int p = 0; p < 4; ++p) {
      const int mq = p >> 1, nq = p & 1;
      if (p == 0) {
        #pragma unroll
        for (int nj = 0; nj < 4; ++nj)
          #pragma unroll
          for (int ks = 0; ks < 2; ++ks)
            breg_all[nj][ks] = *(const s16x8*)(Bbase + ldsoff(wcol + nj * 16 + fr, ks));
      }
      if (nq == 0) {
        #pragma unroll
        for (int i = 0; i < 4; ++i)
          #pragma unroll
          for (int ks = 0; ks < 2; ++ks)
            areg[i][ks] = *(const s16x8*)(Abase + ldsoff(wrow + (mq * 4 + i) * 16 + fr, ks));
      }
      // ---- staging ----
      if constexpr (AF32) {
        if (p == 0 && t + 1 < NT) ldA4(t + 1, 1, rA1);
        if (p == 1 && t + 1 < NT) {
          asm volatile("s_waitcnt vmcnt(4)" ::: "memory");   // A0ld(t+1) done
          wrA(t + 1, 0, rA0);
          stB(t + 1, 0);
        }
        if (p == 2 && t + 1 < NT) {
          asm volatile("s_waitcnt vmcnt(2)" ::: "memory");   // A1ld(t+1) done
          wrA(t + 1, 1, rA1);
          stB(t + 1, 1);
        }
        if (p == 3 && t + 2 < NT) ldA4(t + 2, 0, rA0);
      } else {
        if (p == 0 && t + 1 < NT) stA(t + 1, 1);
        if (p == 1 && t + 1 < NT) stB(t + 1, 0);
        if (p == 2 && t + 1 < NT) stB(t + 1, 1);
        if (p == 3 && t + 2 < NT) stA(t + 2, 0);
      }

      asm volatile("s_barrier" ::: "memory");
      __builtin_amdgcn_s_setprio(1);
      #pragma unroll
      for (int i = 0; i < 4; ++i)
        #pragma unroll
        for (int j = 0; j < 2; ++j)
          #pragma unroll
          for (int ks = 0; ks < 2; ++ks)
            acc[mq * 4 + i][nq * 2 + j] = __builtin_amdgcn_mfma_f32_16x16x32_bf16(
                areg[i][ks], breg_all[nq * 2 + j][ks], acc[mq * 4 + i][nq * 2 + j], 0, 0, 0);
      __builtin_amdgcn_s_setprio(0);
      if (p < 3) {
        asm volatile("s_barrier" ::: "memory");
      } else {
        if constexpr (AF32) {
          if (t + 1 < NT) {
            if (t == NT - 2) asm volatile("s_waitcnt vmcnt(0)" ::: "memory");
            else             asm volatile("s_waitcnt vmcnt(4)" ::: "memory");
            asm volatile("s_waitcnt lgkmcnt(0)" ::: "memory");
          }
        } else {
          if (t == NT - 2) asm volatile("s_waitcnt vmcnt(0)" ::: "memory");
          else             asm volatile("s_waitcnt vmcnt(2)" ::: "memory");
        }
        asm volatile("s_barrier" ::: "memory");
      }
    }
  }

  // ---- epilogue ----
  if constexpr (MODE == 0) {
    #pragma unroll
    for (int ni = 0; ni < 4; ++ni) {
      const int col = n0 + wcol + ni * 16 + fr;
      const float bvv = bias[col];
      #pragma unroll
      for (int mi = 0; mi < 8; ++mi)
        #pragma unroll
        for (int r = 0; r < 4; ++r)
          acc[mi][ni][r] += bvv;
    }
    #pragma unroll
    for (int ni = 0; ni < 4; ++ni) {
      const int col = n0 + wcol + ni * 16 + fr;
      #pragma unroll
      for (int mi = 0; mi < 8; ++mi) {
        #pragma unroll
        for (int r = 0; r < 4; ++r) {
          const int row = m0 + wrow + mi * 16 + fq * 4 + r;
          Cb[(size_t)row * DIM + col] = f2bf(acc[mi][ni][r]);
        }
      }
    }
    if (do_alpha) {
      const int h = (n0 >> 6) + wc;
      float qa0 = qalpha[h * HDIM + 0 * 16 + fr];
      float qa1 = qalpha[h * HDIM + 1 * 16 + fr];
      float qa2 = qalpha[h * HDIM + 2 * 16 + fr];
      float qa3 = qalpha[h * HDIM + 3 * 16 + fr];
      #pragma unroll
      for (int mi = 0; mi < 8; ++mi) {
        #pragma unroll
        for (int r = 0; r < 4; ++r) {
          float p = acc[mi][0][r] * qa0 + acc[mi][1][r] * qa1
                  + acc[mi][2][r] * qa2 + acc[mi][3][r] * qa3;
          p += __shfl_xor(p, 1);
          p += __shfl_xor(p, 2);
          p += __shfl_xor(p, 4);
          p += __shfl_xor(p, 8);
          if (fr == 0) {
            const int row = m0 + wrow + mi * 16 + fq * 4 + r;
            la[((size_t)(row >> 12) * NHEAD + h) * SEQ + (row & (SEQ - 1))] = p * SCALEF;
          }
        }
      }
    }
  } else {
    const int bidx = m0 >> 12;
    #pragma unroll
    for (int ni = 0; ni < 4; ++ni) {
      const int col = n0 + wcol + ni * 16 + fr;
      const float cv = c2[bidx * DIM + col];
      #pragma unroll
      for (int mi = 0; mi < 8; ++mi) {
        #pragma unroll
        for (int r = 0; r < 4; ++r) {
          const int row = m0 + wrow + mi * 16 + fq * 4 + r;
          Cf[(size_t)row * DIM + col] = acc[mi][ni][r] + cv;
        }
      }
    }
  }
}

// ---------------------------------------------------------------------------
// Softmax normalize l[bh][0..SEQ) in place; zero zbuf[bh][64]. 64 blocks.
// ---------------------------------------------------------------------------
__global__ __launch_bounds__(256) void softmax_norm(
    float* __restrict__ l, float* __restrict__ zbuf)
{
  const int bh = blockIdx.x;
  const int tid = threadIdx.x, lane = tid & 63, wave = tid >> 6;
  float* p = l + (size_t)bh * SEQ;
  __shared__ float red[8];

  float4 v[4];
  #pragma unroll
  for (int i = 0; i < 4; ++i) v[i] = ((const float4*)p)[i * 256 + tid];

  float m = -1e30f;
  #pragma unroll
  for (int i = 0; i < 4; ++i)
    m = fmaxf(m, fmaxf(fmaxf(v[i].x, v[i].y), fmaxf(v[i].z, v[i].w)));
  #pragma unroll
  for (int o = 32; o; o >>= 1) m = fmaxf(m, __shfl_xor(m, o));
  if (lane == 0) red[wave] = m;
  __syncthreads();
  m = fmaxf(fmaxf(red[0], red[1]), fmaxf(red[2], red[3]));

  float s = 0.f;
  #pragma unroll
  for (int i = 0; i < 4; ++i) {
    v[i].x = __expf(v[i].x - m); v[i].y = __expf(v[i].y - m);
    v[i].z = __expf(v[i].z - m); v[i].w = __expf(v[i].w - m);
    s += (v[i].x + v[i].y) + (v[i].z + v[i].w);
  }
  #pragma unroll
  for (int o = 32; o; o >>= 1) s += __shfl_xor(s, o);
  if (lane == 0) red[4 + wave] = s;
  __syncthreads();
  s = (red[4] + red[5]) + (red[6] + red[7]);

  float inv = 1.0f / s;
  #pragma unroll
  for (int i = 0; i < 4; ++i) {
    v[i].x *= inv; v[i].y *= inv; v[i].z *= inv; v[i].w *= inv;
    ((float4*)p)[i * 256 + tid] = v[i];
  }
  if (tid < HDIM) zbuf[bh * HDIM + tid] = 0.f;
}

// ---------------------------------------------------------------------------
// outp[bh][d] += sum_n w[bh][n] * X[b][n][h*64+d].  grid (8 chunks, 64 bh).
// ---------------------------------------------------------------------------
__global__ __launch_bounds__(256) void accum_weighted(
    const u16* __restrict__ X, const float* __restrict__ w,
    float* __restrict__ outp)
{
  const int bh = blockIdx.y, chunk = blockIdx.x;
  const int b = bh >> 4, h = bh & 15;
  const int tid = threadIdx.x, lane = tid & 63, wave = tid >> 6;
  const int rsub = lane >> 3, cl = lane & 7;
  const size_t base = (size_t)b * SEQ * DIM + h * HDIM;
  const int n0 = chunk * 512;

  float acc[8] = {0, 0, 0, 0, 0, 0, 0, 0};
  for (int it = 0; it < 16; ++it) {
    int n = n0 + it * 32 + wave * 8 + rsub;
    u16x8 u = *(const u16x8*)(X + base + (size_t)n * DIM + cl * 8);
    float wv = w[(size_t)bh * SEQ + n];
    #pragma unroll
    for (int j = 0; j < 8; ++j) acc[j] += wv * bf2f(u[j]);
  }
  #pragma unroll
  for (int j = 0; j < 8; ++j) {
    acc[j] += __shfl_xor(acc[j], 8);
    acc[j] += __shfl_xor(acc[j], 16);
    acc[j] += __shfl_xor(acc[j], 32);
  }
  __shared__ float part[4][64];
  if (rsub == 0) {
    #pragma unroll
    for (int j = 0; j < 8; ++j) part[wave][cl * 8 + j] = acc[j];
  }
  __syncthreads();
  if (tid < HDIM) {
    float s = (part[0][tid] + part[1][tid]) + (part[2][tid] + part[3][tid]);
    atomicAdd(&outp[bh * HDIM + tid], s);
  }
}

// ---------------------------------------------------------------------------
// Beta logits: lb[b*16+h][n] = dot(K[b][n][h*64:+64], gq[b]⊙kbeta·SCALE).
// ---------------------------------------------------------------------------
__global__ __launch_bounds__(256) void logits_beta(
    const u16* __restrict__ Kb, const float* __restrict__ gq,
    const float* __restrict__ kbeta, float* __restrict__ lb)
{
  __shared__ float vb[NHEAD][HDIM];
  const int rg = blockIdx.x;
  const int b = rg >> 8;
  const int tid = threadIdx.x, lane = tid & 63, wave = tid >> 6;

  for (int i = tid; i < NHEAD * HDIM; i += 256)
    ((float*)vb)[i] = gq[b * DIM + i] * kbeta[i] * SCALEF;
  __syncthreads();

  const int h = lane >> 2, dq = (lane & 3) * 16;
  #pragma unroll
  for (int i = 0; i < 4; ++i) {
    int gr = rg * 16 + wave * 4 + i;
    const u16* rp = Kb + (size_t)gr * DIM + h * HDIM + dq;
    u16x8 u0 = *(const u16x8*)rp;
    u16x8 u1 = *(const u16x8*)(rp + 8);
    float dot = 0.f;
    #pragma unroll
    for (int j = 0; j < 8; ++j) dot += bf2f(u0[j]) * vb[h][dq + j];
    #pragma unroll
    for (int j = 0; j < 8; ++j) dot += bf2f(u1[j]) * vb[h][dq + 8 + j];
    dot += __shfl_xor(dot, 1);
    dot += __shfl_xor(dot, 2);
    if ((lane & 3) == 0) {
      lb[((size_t)b * NHEAD + h) * SEQ + (gr & (SEQ - 1))] = dot;
    }
  }
}

// ---------------------------------------------------------------------------
// c2[b,j] = sum_k gv[b,k]*Wo[j,k] + bo[j].  One wave per (b,j); 1024 blocks.
// ---------------------------------------------------------------------------
__global__ __launch_bounds__(256) void gv_wo_kernel(
    const float* __restrict__ gv, const float* __restrict__ Wo,
    const float* __restrict__ bo, float* __restrict__ c2)
{
  int wid = blockIdx.x * 4 + (threadIdx.x >> 6);
  int b = wid >> 10, j = wid & 1023;
  int lane = threadIdx.x & 63;
  float acc = 0.f;
  #pragma unroll
  for (int c = 0; c < 16; ++c) {
    int kk = c * 64 + lane;
    acc += gv[b * DIM + kk] * Wo[(size_t)j * DIM + kk];
  }
  #pragma unroll
  for (int o = 32; o; o >>= 1) acc += __shfl_down(acc, o);
  if (lane == 0) c2[wid] = acc + bo[j];
}

// ---------------------------------------------------------------------------
extern "C" void kernel_launch(void* const* d_in, const int* in_sizes, int n_in,
                              void* d_out, int out_size, void* d_ws, size_t ws_size,
                              hipStream_t stream) {
  const float* q  = (const float*)d_in[0];
  const float* k  = (const float*)d_in[1];
  const float* v  = (const float*)d_in[2];
  const float* Wq = (const float*)d_in[3];
  const float* bq = (const float*)d_in[4];
  const float* Wk = (const float*)d_in[5];
  const float* bk = (const float*)d_in[6];
  const float* Wv = (const float*)d_in[7];
  const float* bv = (const float*)d_in[8];
  const float* qa = (const float*)d_in[9];
  const float* kb = (const float*)d_in[10];
  const float* Wo = (const float*)d_in[11];
  const float* bo = (const float*)d_in[12];
  float* out = (float*)d_out;

  // workspace layout (~111 MB)
  u16* Qb  = (u16*)d_ws;
  u16* Kb  = Qb + (size_t)MROWS * DIM;
  u16* Vb  = Kb + (size_t)MROWS * DIM;
  u16* Wqb = Vb + (size_t)MROWS * DIM;
  u16* Wkb = Wqb + (size_t)DIM * DIM;
  u16* Wvb = Wkb + (size_t)DIM * DIM;
  u16* Wob = Wvb + (size_t)DIM * DIM;
  float* la   = (float*)(Wob + (size_t)DIM * DIM);
  float* lb   = la + (size_t)NB * NHEAD * SEQ;
  float* gq   = lb + (size_t)NB * NHEAD * SEQ;
  float* gv   = gq + NB * DIM;
  float* c2   = gv + NB * DIM;

  const dim3 g256(MROWS / 256, DIM / 256);   // (64, 4)
  const size_t ldsb = 131072;

  cvt_weights<<<2048, 256, 0, stream>>>(Wq, Wk, Wv, Wo, Wqb, Wkb, Wvb, Wob);

  // QKV projections: fp32 activations consumed directly (reg-staged cvt)
  gemm256<0, 1><<<g256, 512, ldsb, stream>>>(nullptr, Wqb, bq, Qb, nullptr,
                                             nullptr, 1, qa, la, q);
  gemm256<0, 1><<<g256, 512, ldsb, stream>>>(nullptr, Wkb, bk, Kb, nullptr,
                                             nullptr, 0, qa, la, k);
  gemm256<0, 1><<<g256, 512, ldsb, stream>>>(nullptr, Wvb, bv, Vb, nullptr,
                                             nullptr, 0, qa, la, v);

  softmax_norm<<<64, 256, 0, stream>>>(la, gq);
  accum_weighted<<<dim3(8, 64), 256, 0, stream>>>(Qb, la, gq);
  logits_beta<<<1024, 256, 0, stream>>>(Kb, gq, kb, lb);
  softmax_norm<<<64, 256, 0, stream>>>(lb, gv);
  accum_weighted<<<dim3(8, 64), 256, 0, stream>>>(Vb, lb, gv);
  gv_wo_kernel<<<1024, 256, 0, stream>>>(gv, Wo, bo, c2);
  gemm256<1, 0><<<g256, 512, ldsb, stream>>>(Qb, Wob, nullptr, nullptr, out,
                                             c2, 0, qa, la, nullptr);
}

// Round 13
// 239.947 us; speedup vs baseline: 1.0836x; 1.0836x over previous
//
#include <hip/hip_runtime.h>
#include <hip/hip_bf16.h>
#include <cstdint>
#include <cstddef>

// Problem constants
#define SEQ    4096
#define NB     4
#define DIM    1024
#define NHEAD  16
#define HDIM   64
#define MROWS  (NB * SEQ)   // 16384
#define SCALEF 0.125f       // 64^-0.5
#define NT     16           // K tiles of 64

typedef short          s16x8 __attribute__((ext_vector_type(8)));
typedef unsigned short u16x8 __attribute__((ext_vector_type(8)));
typedef float          f32x4 __attribute__((ext_vector_type(4)));
typedef unsigned short u16;

__device__ __forceinline__ u16 f2bf(float f) {
  return __builtin_bit_cast(u16, __float2bfloat16(f));
}
__device__ __forceinline__ float bf2f(u16 u) {
  return __builtin_bit_cast(float, (uint32_t)u << 16);
}
__device__ __forceinline__ void gload_lds16(const void* g, void* l) {
  __builtin_amdgcn_global_load_lds(
      (const __attribute__((address_space(1))) void*)g,
      (__attribute__((address_space(3))) void*)l, 16, 0, 0);
}

// ---------------------------------------------------------------------------
// Convert the four [DIM,DIM] fp32 weight matrices to bf16.
// ---------------------------------------------------------------------------
__global__ __launch_bounds__(256) void cvt_weights(
    const float* __restrict__ w0, const float* __restrict__ w1,
    const float* __restrict__ w2, const float* __restrict__ w3,
    u16* __restrict__ o0, u16* __restrict__ o1,
    u16* __restrict__ o2, u16* __restrict__ o3)
{
  int t = blockIdx.x * 256 + threadIdx.x;
  int m = t >> 17;
  int off = (t & 131071) * 8;
  const float* s = (m == 0) ? w0 : (m == 1) ? w1 : (m == 2) ? w2 : w3;
  u16*         d = (m == 0) ? o0 : (m == 1) ? o1 : (m == 2) ? o2 : o3;
  float4 a = ((const float4*)(s + off))[0];
  float4 b = ((const float4*)(s + off))[1];
  u16x8 p;
  p[0] = f2bf(a.x); p[1] = f2bf(a.y); p[2] = f2bf(a.z); p[3] = f2bf(a.w);
  p[4] = f2bf(b.x); p[5] = f2bf(b.y); p[6] = f2bf(b.z); p[7] = f2bf(b.w);
  *(u16x8*)(d + off) = p;
}

// ---------------------------------------------------------------------------
// Convert ONE or TWO [MROWS,DIM] fp32 activation matrices to bf16.
// grid 8192 (s1==null) or 16384 blocks: blocks [0,8192) -> s0, rest -> s1.
// ---------------------------------------------------------------------------
__global__ __launch_bounds__(256) void cvt_act2(
    const float* __restrict__ s0, u16* __restrict__ d0,
    const float* __restrict__ s1, u16* __restrict__ d1)
{
  const int bid = blockIdx.x;
  const float* s = (bid < 8192) ? s0 : s1;
  u16*         d = (bid < 8192) ? d0 : d1;
  int t = (bid & 8191) * 256 + threadIdx.x;
  int off = t * 8;
  float4 a = ((const float4*)(s + off))[0];
  float4 b = ((const float4*)(s + off))[1];
  u16x8 p;
  p[0] = f2bf(a.x); p[1] = f2bf(a.y); p[2] = f2bf(a.z); p[3] = f2bf(a.w);
  p[4] = f2bf(b.x); p[5] = f2bf(b.y); p[6] = f2bf(b.z); p[7] = f2bf(b.w);
  *(u16x8*)(d + off) = p;
}

// ---------------------------------------------------------------------------
// 256x256-tile phase-split GEMM (T2+T3+T4+T5), BK=64, 8 waves (2Mx4N), 512thr.
// LDS (dynamic 128KB): A[2][256][64] bf16 @0, B[2][256][64] bf16 @65536.
// T2 swizzle both-sides (verified r6: bank conflicts 1.26e7 -> 0).
// r11: B-fragments hoisted (breg_all loaded once per tile at p0) — verified
// 45.3us/GEMM ~ 765 TF at K=1024 (r11 bench).
// FAILED-PATH LEDGER (do not retry):
//  r7-r9: >512-thread side-job waves -> allocator pins 84 VGPR, acc spills.
//  r12:   AF32 reg-staged A (T14) -> in-phase vmcnt puts HBM latency on the
//         8-wave barrier critical path; 73.6us vs 45.3. gload_lds-only wins.
// MODE 0: C = A@W^T + bias -> bf16 (+optional fused alpha logits).
// MODE 1: C = A@W^T + c2[batch] -> fp32.
// ---------------------------------------------------------------------------
template<int MODE>
__global__ __launch_bounds__(512) void gemm256(
    const u16* __restrict__ A, const u16* __restrict__ W,
    const float* __restrict__ bias, u16* __restrict__ Cb, float* __restrict__ Cf,
    const float* __restrict__ c2, int do_alpha,
    const float* __restrict__ qalpha, float* __restrict__ la)
{
  extern __shared__ __align__(16) char smem[];
  const int tid = threadIdx.x;
  const int lane = tid & 63, wave = tid >> 6;
  const int wr = wave >> 2, wc = wave & 3;          // 2 (M) x 4 (N)
  const int fr = lane & 15, fq = lane >> 4;
  const int m0 = blockIdx.x * 256, n0 = blockIdx.y * 256;
  const int wrow = wr * 128, wcol = wc * 64;

  const int arow = tid >> 3;                         // staging row 0..63
  const int scol = (((tid & 7) ^ ((tid >> 3) & 7)) * 8);  // pre-swizzled src col

  f32x4 acc[8][4];
  #pragma unroll
  for (int i = 0; i < 8; ++i)
    #pragma unroll
    for (int j = 0; j < 4; ++j) acc[i][j] = (f32x4){0.f, 0.f, 0.f, 0.f};

  auto stA = [&](int kt, int h) {
    const u16* g = A + (size_t)(m0 + h * 128) * DIM + kt * 64;
    char* l = smem + (kt & 1) * 32768 + h * 16384;
    gload_lds16(g + (size_t)arow * DIM + scol,        l + tid * 16);
    gload_lds16(g + (size_t)(64 + arow) * DIM + scol, l + 8192 + tid * 16);
  };
  auto stB = [&](int kt, int h) {
    const u16* g = W + (size_t)(n0 + h * 128) * DIM + kt * 64;
    char* l = smem + 65536 + (kt & 1) * 32768 + h * 16384;
    gload_lds16(g + (size_t)arow * DIM + scol,        l + tid * 16);
    gload_lds16(g + (size_t)(64 + arow) * DIM + scol, l + 8192 + tid * 16);
  };
  auto ldsoff = [&](int R, int ks) -> size_t {
    return (size_t)R * 128 + (size_t)((ks * 64 + fq * 16) ^ ((R & 7) << 4));
  };

  stA(0, 0); stA(0, 1); stB(0, 0); stB(0, 1);
  stA(1, 0);
  asm volatile("s_waitcnt vmcnt(2)" ::: "memory");
  asm volatile("s_barrier" ::: "memory");

  for (int t = 0; t < NT; ++t) {
    const char* Abase = smem + (t & 1) * 32768;
    const char* Bbase = smem + 65536 + (t & 1) * 32768;
    s16x8 areg[4][2];
    s16x8 breg_all[4][2];            // all 4 nj x 2 ks, loaded once at p==0
    #pragma unroll
    for (int p = 0; p < 4; ++p) {
      const int mq = p >> 1, nq = p & 1;
      if (p == 0) {
        #pragma unroll
        for (int nj = 0; nj < 4; ++nj)
          #pragma unroll
          for (int ks = 0; ks < 2; ++ks)
            breg_all[nj][ks] = *(const s16x8*)(Bbase + ldsoff(wcol + nj * 16 + fr, ks));
      }
      if (nq == 0) {
        #pragma unroll
        for (int i = 0; i < 4; ++i)
          #pragma unroll
          for (int ks = 0; ks < 2; ++ks)
            areg[i][ks] = *(const s16x8*)(Abase + ldsoff(wrow + (mq * 4 + i) * 16 + fr, ks));
      }
      if (p == 0 && t + 1 < NT) stA(t + 1, 1);
      if (p == 1 && t + 1 < NT) stB(t + 1, 0);
      if (p == 2 && t + 1 < NT) stB(t + 1, 1);
      if (p == 3 && t + 2 < NT) stA(t + 2, 0);

      asm volatile("s_barrier" ::: "memory");
      __builtin_amdgcn_s_setprio(1);
      #pragma unroll
      for (int i = 0; i < 4; ++i)
        #pragma unroll
        for (int j = 0; j < 2; ++j)
          #pragma unroll
          for (int ks = 0; ks < 2; ++ks)
            acc[mq * 4 + i][nq * 2 + j] = __builtin_amdgcn_mfma_f32_16x16x32_bf16(
                areg[i][ks], breg_all[nq * 2 + j][ks], acc[mq * 4 + i][nq * 2 + j], 0, 0, 0);
      __builtin_amdgcn_s_setprio(0);
      if (p < 3) {
        asm volatile("s_barrier" ::: "memory");
      } else {
        if (t == NT - 2) asm volatile("s_waitcnt vmcnt(0)" ::: "memory");
        else             asm volatile("s_waitcnt vmcnt(2)" ::: "memory");
        asm volatile("s_barrier" ::: "memory");
      }
    }
  }

  // ---- epilogue ----
  if constexpr (MODE == 0) {
    #pragma unroll
    for (int ni = 0; ni < 4; ++ni) {
      const int col = n0 + wcol + ni * 16 + fr;
      const float bvv = bias[col];
      #pragma unroll
      for (int mi = 0; mi < 8; ++mi)
        #pragma unroll
        for (int r = 0; r < 4; ++r)
          acc[mi][ni][r] += bvv;
    }
    #pragma unroll
    for (int ni = 0; ni < 4; ++ni) {
      const int col = n0 + wcol + ni * 16 + fr;
      #pragma unroll
      for (int mi = 0; mi < 8; ++mi) {
        #pragma unroll
        for (int r = 0; r < 4; ++r) {
          const int row = m0 + wrow + mi * 16 + fq * 4 + r;
          Cb[(size_t)row * DIM + col] = f2bf(acc[mi][ni][r]);
        }
      }
    }
    if (do_alpha) {
      const int h = (n0 >> 6) + wc;
      float qa0 = qalpha[h * HDIM + 0 * 16 + fr];
      float qa1 = qalpha[h * HDIM + 1 * 16 + fr];
      float qa2 = qalpha[h * HDIM + 2 * 16 + fr];
      float qa3 = qalpha[h * HDIM + 3 * 16 + fr];
      #pragma unroll
      for (int mi = 0; mi < 8; ++mi) {
        #pragma unroll
        for (int r = 0; r < 4; ++r) {
          float p = acc[mi][0][r] * qa0 + acc[mi][1][r] * qa1
                  + acc[mi][2][r] * qa2 + acc[mi][3][r] * qa3;
          p += __shfl_xor(p, 1);
          p += __shfl_xor(p, 2);
          p += __shfl_xor(p, 4);
          p += __shfl_xor(p, 8);
          if (fr == 0) {
            const int row = m0 + wrow + mi * 16 + fq * 4 + r;
            la[((size_t)(row >> 12) * NHEAD + h) * SEQ + (row & (SEQ - 1))] = p * SCALEF;
          }
        }
      }
    }
  } else {
    const int bidx = m0 >> 12;
    #pragma unroll
    for (int ni = 0; ni < 4; ++ni) {
      const int col = n0 + wcol + ni * 16 + fr;
      const float cv = c2[bidx * DIM + col];
      #pragma unroll
      for (int mi = 0; mi < 8; ++mi) {
        #pragma unroll
        for (int r = 0; r < 4; ++r) {
          const int row = m0 + wrow + mi * 16 + fq * 4 + r;
          Cf[(size_t)row * DIM + col] = acc[mi][ni][r] + cv;
        }
      }
    }
  }
}

// ---------------------------------------------------------------------------
// Softmax normalize l[bh][0..SEQ) in place; zero zbuf[bh][64]. 64 blocks.
// ---------------------------------------------------------------------------
__global__ __launch_bounds__(256) void softmax_norm(
    float* __restrict__ l, float* __restrict__ zbuf)
{
  const int bh = blockIdx.x;
  const int tid = threadIdx.x, lane = tid & 63, wave = tid >> 6;
  float* p = l + (size_t)bh * SEQ;
  __shared__ float red[8];

  float4 v[4];
  #pragma unroll
  for (int i = 0; i < 4; ++i) v[i] = ((const float4*)p)[i * 256 + tid];

  float m = -1e30f;
  #pragma unroll
  for (int i = 0; i < 4; ++i)
    m = fmaxf(m, fmaxf(fmaxf(v[i].x, v[i].y), fmaxf(v[i].z, v[i].w)));
  #pragma unroll
  for (int o = 32; o; o >>= 1) m = fmaxf(m, __shfl_xor(m, o));
  if (lane == 0) red[wave] = m;
  __syncthreads();
  m = fmaxf(fmaxf(red[0], red[1]), fmaxf(red[2], red[3]));

  float s = 0.f;
  #pragma unroll
  for (int i = 0; i < 4; ++i) {
    v[i].x = __expf(v[i].x - m); v[i].y = __expf(v[i].y - m);
    v[i].z = __expf(v[i].z - m); v[i].w = __expf(v[i].w - m);
    s += (v[i].x + v[i].y) + (v[i].z + v[i].w);
  }
  #pragma unroll
  for (int o = 32; o; o >>= 1) s += __shfl_xor(s, o);
  if (lane == 0) red[4 + wave] = s;
  __syncthreads();
  s = (red[4] + red[5]) + (red[6] + red[7]);

  float inv = 1.0f / s;
  #pragma unroll
  for (int i = 0; i < 4; ++i) {
    v[i].x *= inv; v[i].y *= inv; v[i].z *= inv; v[i].w *= inv;
    ((float4*)p)[i * 256 + tid] = v[i];
  }
  if (tid < HDIM) zbuf[bh * HDIM + tid] = 0.f;
}

// ---------------------------------------------------------------------------
// outp[bh][d] += sum_n w[bh][n] * X[b][n][h*64+d].  grid (8 chunks, 64 bh).
// ---------------------------------------------------------------------------
__global__ __launch_bounds__(256) void accum_weighted(
    const u16* __restrict__ X, const float* __restrict__ w,
    float* __restrict__ outp)
{
  const int bh = blockIdx.y, chunk = blockIdx.x;
  const int b = bh >> 4, h = bh & 15;
  const int tid = threadIdx.x, lane = tid & 63, wave = tid >> 6;
  const int rsub = lane >> 3, cl = lane & 7;
  const size_t base = (size_t)b * SEQ * DIM + h * HDIM;
  const int n0 = chunk * 512;

  float acc[8] = {0, 0, 0, 0, 0, 0, 0, 0};
  for (int it = 0; it < 16; ++it) {
    int n = n0 + it * 32 + wave * 8 + rsub;
    u16x8 u = *(const u16x8*)(X + base + (size_t)n * DIM + cl * 8);
    float wv = w[(size_t)bh * SEQ + n];
    #pragma unroll
    for (int j = 0; j < 8; ++j) acc[j] += wv * bf2f(u[j]);
  }
  #pragma unroll
  for (int j = 0; j < 8; ++j) {
    acc[j] += __shfl_xor(acc[j], 8);
    acc[j] += __shfl_xor(acc[j], 16);
    acc[j] += __shfl_xor(acc[j], 32);
  }
  __shared__ float part[4][64];
  if (rsub == 0) {
    #pragma unroll
    for (int j = 0; j < 8; ++j) part[wave][cl * 8 + j] = acc[j];
  }
  __syncthreads();
  if (tid < HDIM) {
    float s = (part[0][tid] + part[1][tid]) + (part[2][tid] + part[3][tid]);
    atomicAdd(&outp[bh * HDIM + tid], s);
  }
}

// ---------------------------------------------------------------------------
// Beta logits: lb[b*16+h][n] = dot(K[b][n][h*64:+64], gq[b]⊙kbeta·SCALE).
// ---------------------------------------------------------------------------
__global__ __launch_bounds__(256) void logits_beta(
    const u16* __restrict__ Kb, const float* __restrict__ gq,
    const float* __restrict__ kbeta, float* __restrict__ lb)
{
  __shared__ float vb[NHEAD][HDIM];
  const int rg = blockIdx.x;
  const int b = rg >> 8;
  const int tid = threadIdx.x, lane = tid & 63, wave = tid >> 6;

  for (int i = tid; i < NHEAD * HDIM; i += 256)
    ((float*)vb)[i] = gq[b * DIM + i] * kbeta[i] * SCALEF;
  __syncthreads();

  const int h = lane >> 2, dq = (lane & 3) * 16;
  #pragma unroll
  for (int i = 0; i < 4; ++i) {
    int gr = rg * 16 + wave * 4 + i;
    const u16* rp = Kb + (size_t)gr * DIM + h * HDIM + dq;
    u16x8 u0 = *(const u16x8*)rp;
    u16x8 u1 = *(const u16x8*)(rp + 8);
    float dot = 0.f;
    #pragma unroll
    for (int j = 0; j < 8; ++j) dot += bf2f(u0[j]) * vb[h][dq + j];
    #pragma unroll
    for (int j = 0; j < 8; ++j) dot += bf2f(u1[j]) * vb[h][dq + 8 + j];
    dot += __shfl_xor(dot, 1);
    dot += __shfl_xor(dot, 2);
    if ((lane & 3) == 0) {
      lb[((size_t)b * NHEAD + h) * SEQ + (gr & (SEQ - 1))] = dot;
    }
  }
}

// ---------------------------------------------------------------------------
// c2[b,j] = sum_k gv[b,k]*Wo[j,k] + bo[j].  One wave per (b,j); 1024 blocks.
// ---------------------------------------------------------------------------
__global__ __launch_bounds__(256) void gv_wo_kernel(
    const float* __restrict__ gv, const float* __restrict__ Wo,
    const float* __restrict__ bo, float* __restrict__ c2)
{
  int wid = blockIdx.x * 4 + (threadIdx.x >> 6);
  int b = wid >> 10, j = wid & 1023;
  int lane = threadIdx.x & 63;
  float acc = 0.f;
  #pragma unroll
  for (int c = 0; c < 16; ++c) {
    int kk = c * 64 + lane;
    acc += gv[b * DIM + kk] * Wo[(size_t)j * DIM + kk];
  }
  #pragma unroll
  for (int o = 32; o; o >>= 1) acc += __shfl_down(acc, o);
  if (lane == 0) c2[wid] = acc + bo[j];
}

// ---------------------------------------------------------------------------
extern "C" void kernel_launch(void* const* d_in, const int* in_sizes, int n_in,
                              void* d_out, int out_size, void* d_ws, size_t ws_size,
                              hipStream_t stream) {
  const float* q  = (const float*)d_in[0];
  const float* k  = (const float*)d_in[1];
  const float* v  = (const float*)d_in[2];
  const float* Wq = (const float*)d_in[3];
  const float* bq = (const float*)d_in[4];
  const float* Wk = (const float*)d_in[5];
  const float* bk = (const float*)d_in[6];
  const float* Wv = (const float*)d_in[7];
  const float* bv = (const float*)d_in[8];
  const float* qa = (const float*)d_in[9];
  const float* kb = (const float*)d_in[10];
  const float* Wo = (const float*)d_in[11];
  const float* bo = (const float*)d_in[12];
  float* out = (float*)d_out;

  // workspace layout (~111 MB)
  u16* Qb  = (u16*)d_ws;
  u16* Kb  = Qb + (size_t)MROWS * DIM;
  u16* Vb  = Kb + (size_t)MROWS * DIM;
  u16* Wqb = Vb + (size_t)MROWS * DIM;
  u16* Wkb = Wqb + (size_t)DIM * DIM;
  u16* Wvb = Wkb + (size_t)DIM * DIM;
  u16* Wob = Wvb + (size_t)DIM * DIM;
  float* la   = (float*)(Wob + (size_t)DIM * DIM);
  float* lb   = la + (size_t)NB * NHEAD * SEQ;
  float* gq   = lb + (size_t)NB * NHEAD * SEQ;
  float* gv   = gq + NB * DIM;
  float* c2   = gv + NB * DIM;

  // two bf16 activation buffers in d_out (67.1MB = exactly 2 x 33.55MB);
  // b0: q then v (b0 dead after gemm(Q)); b1: k.
  u16* actb0 = (u16*)d_out;
  u16* actb1 = actb0 + (size_t)MROWS * DIM;

  const dim3 g256(MROWS / 256, DIM / 256);   // (64, 4)
  const size_t ldsb = 131072;

  cvt_weights<<<2048, 256, 0, stream>>>(Wq, Wk, Wv, Wo, Wqb, Wkb, Wvb, Wob);
  cvt_act2<<<16384, 256, 0, stream>>>(q, actb0, k, actb1);   // q and k in one pass

  gemm256<0><<<g256, 512, ldsb, stream>>>(actb0, Wqb, bq, Qb, nullptr, nullptr, 1, qa, la);
  cvt_act2<<<8192, 256, 0, stream>>>(v, actb0, nullptr, nullptr);
  gemm256<0><<<g256, 512, ldsb, stream>>>(actb1, Wkb, bk, Kb, nullptr, nullptr, 0, qa, la);
  gemm256<0><<<g256, 512, ldsb, stream>>>(actb0, Wvb, bv, Vb, nullptr, nullptr, 0, qa, la);

  softmax_norm<<<64, 256, 0, stream>>>(la, gq);
  accum_weighted<<<dim3(8, 64), 256, 0, stream>>>(Qb, la, gq);
  logits_beta<<<1024, 256, 0, stream>>>(Kb, gq, kb, lb);
  softmax_norm<<<64, 256, 0, stream>>>(lb, gv);
  accum_weighted<<<dim3(8, 64), 256, 0, stream>>>(Vb, lb, gv);
  gv_wo_kernel<<<1024, 256, 0, stream>>>(gv, Wo, bo, c2);
  gemm256<1><<<g256, 512, ldsb, stream>>>(Qb, Wob, nullptr, nullptr, out, c2, 0, qa, la);
}